// Round 11
// baseline (1529.067 us; speedup 1.0000x reference)
//
#include <hip/hip_runtime.h>

#define NN      100000      // nodes
#define NN2     100096      // nodes padded to 128 (782 tiles)
#define NE      400000      // raw edges
#define ETOT    500000      // edges + self loops
#define NG      4000        // graphs
#define W3D     384
#define HIDD    128
#define NCLS    10
#define NSLICE  256         // stat accumulation slices

typedef unsigned short u16;
typedef unsigned int   u32;
typedef unsigned long long u64;
typedef __attribute__((ext_vector_type(8))) short short8;
typedef __attribute__((ext_vector_type(4))) float f32x4;

static __device__ __forceinline__ float bf2f(u16 u) {
  return __uint_as_float(((u32)u) << 16);
}
static __device__ __forceinline__ float bflo(u32 u) {
  return __uint_as_float(u << 16);
}
static __device__ __forceinline__ float bfhi(u32 u) {
  return __uint_as_float(u & 0xffff0000u);
}
static __device__ __forceinline__ u16 f2b(float f) {
  u32 u = __float_as_uint(f);
  u32 r = (u + 0x7fffu + ((u >> 16) & 1u)) >> 16;
  return (u16)r;
}

// ---------------------------------------------------------------- fallback
__global__ void mg_zero_out(float* out, int n) {
  int i = blockIdx.x * 256 + threadIdx.x;
  if (i < n) out[i] = 0.f;
}

// ---------------------------------------------------------------- x -> bf16 [NN2][64] zero-padded
__global__ void mg_cvt_x(const float* __restrict__ x, u16* __restrict__ Xb) {
  int idx = blockIdx.x * 256 + threadIdx.x;
  if (idx >= NN2 * 64) return;
  int row = idx >> 6, col = idx & 63;
  Xb[idx] = (row < NN && col < 32) ? f2b(x[row * 32 + col]) : (u16)0;
}

// ---------------------------------------------------------------- transpose
// out[n][k] = bf16(in[k][n]), zero-padded to Kpad. in is fp32.
__global__ void mg_transpose_pad(const float* __restrict__ in, u16* __restrict__ out,
                                 int K, int Nn, int Kpad) {
  int idx = blockIdx.x * 256 + threadIdx.x;
  if (idx >= Nn * Kpad) return;
  int n = idx / Kpad, k = idx - n * Kpad;
  out[idx] = (k < K) ? f2b(in[k * Nn + n]) : (u16)0;
}

// ---------------------------------------------------------------- BN -> weight fold
// Wp[j][k] = Wt[j][k]*scale[k];  bp[j] = sum_k shift[k]*Wt[j][k]
__global__ void mg_fold_w(const u16* __restrict__ Wt, const float* __restrict__ scale,
                          const float* __restrict__ shift, u16* __restrict__ Wp,
                          float* __restrict__ bp) {
  __shared__ float red[128];
  int j = blockIdx.x, t = threadIdx.x;   // 384 blocks x 128 threads
  const u16* src = Wt + (size_t)j * W3D;
  u16* dst = Wp + (size_t)j * W3D;
  float acc = 0.f;
  for (int k = t; k < W3D; k += 128) {
    float w = bf2f(src[k]);
    dst[k] = f2b(w * scale[k]);
    acc += w * shift[k];
  }
  red[t] = acc; __syncthreads();
  for (int off = 64; off; off >>= 1) {
    if (t < off) red[t] += red[t + off];
    __syncthreads();
  }
  if (t == 0) bp[j] = red[0];
}

// ---------------------------------------------------------------- CSR build
__global__ void mg_edge_histo(const int* __restrict__ ei, int* __restrict__ deg) {
  int e = blockIdx.x * 256 + threadIdx.x;
  if (e >= ETOT) return;
  int d = (e < NE) ? ei[NE + e] : (e - NE);
  atomicAdd(&deg[d], 1);
}

__global__ void mg_scan1(const int* __restrict__ in, int* __restrict__ bsum, int n) {
  __shared__ int sd[256];
  int tid = threadIdx.x;
  int base = blockIdx.x * 1024 + tid * 4;
  int s = 0;
#pragma unroll
  for (int j = 0; j < 4; ++j) { int i = base + j; if (i < n) s += in[i]; }
  sd[tid] = s; __syncthreads();
  for (int off = 128; off > 0; off >>= 1) {
    if (tid < off) sd[tid] += sd[tid + off];
    __syncthreads();
  }
  if (tid == 0) bsum[blockIdx.x] = sd[0];
}

__global__ void mg_scan2(int* __restrict__ bsum, int nb) {
  __shared__ int sd[256];
  int tid = threadIdx.x;
  int v = (tid < nb) ? bsum[tid] : 0;
  sd[tid] = v; __syncthreads();
  for (int off = 1; off < 256; off <<= 1) {
    int t = (tid >= off) ? sd[tid - off] : 0;
    __syncthreads();
    sd[tid] += t;
    __syncthreads();
  }
  if (tid < nb) bsum[tid] = sd[tid] - v;   // exclusive
}

__global__ void mg_scan3(const int* __restrict__ in, const int* __restrict__ bexcl,
                         int* __restrict__ out, int n) {
  __shared__ int sd[256];
  int tid = threadIdx.x;
  int base = blockIdx.x * 1024 + tid * 4;
  int loc[4]; int s = 0;
#pragma unroll
  for (int j = 0; j < 4; ++j) { int i = base + j; loc[j] = (i < n) ? in[i] : 0; s += loc[j]; }
  sd[tid] = s; __syncthreads();
  for (int off = 1; off < 256; off <<= 1) {
    int t = (tid >= off) ? sd[tid - off] : 0;
    __syncthreads();
    sd[tid] += t;
    __syncthreads();
  }
  int run = sd[tid] - s + bexcl[blockIdx.x];
#pragma unroll
  for (int j = 0; j < 4; ++j) {
    int i = base + j;
    if (i < n) { out[i] = run; run += loc[j]; if (i == n - 1) out[n] = run; }
  }
}

__global__ void mg_edge_scatter(const int* __restrict__ ei, int* __restrict__ fill,
                                int* __restrict__ colsrc) {
  int e = blockIdx.x * 256 + threadIdx.x;
  if (e >= ETOT) return;
  int s, d;
  if (e < NE) { s = ei[e]; d = ei[NE + e]; } else { s = e - NE; d = s; }
  int pos = atomicAdd(&fill[d], 1);
  colsrc[pos] = s;
}

__global__ void mg_graph_ptr(const int* __restrict__ batch, int* __restrict__ gptr) {
  int g = blockIdx.x * 256 + threadIdx.x;
  if (g > NG) return;
  if (g == NG) { gptr[NG] = NN; return; }
  int lo = 0, hi = NN;
  while (lo < hi) { int mid = (lo + hi) >> 1; if (batch[mid] < g) lo = mid + 1; else hi = mid; }
  gptr[g] = lo;
}

// ---------------------------------------------------------------- GEMM (bf16 MFMA)
// C = A @ B; A bf16 [NN2][K] row-padded, Bt bf16 [Nn][K]. K % 64 == 0.
// 256 threads, 4 waves, tile 128x128, wave tile 64x64, GBK=64.
// REGISTER-STAGED pipeline (single 32 KB LDS buffer):
//   gload r(0)
//   loop { sync; ds_write r; gload r(it+1); sync; compute(it) }
// The vmcnt wait moves from the barrier to each wave's ds_write — by then the
// loads have had a full compute phase to land; barriers drain only LDS ops.
// Staging map: thread (wv,lane), slot j: supergroup g=wv*4+j (8 rows x 64 k),
// row g*8+(lane&7), k-chunk lane>>3; LDS addr g*512 + lane*8 (u16) -> lane-
// linear ds_write_b128 (conflict-free). Compute reads the measured-0-conflict
// pattern (r>>3)*512 + ca*64 + (r&7)*8. Epilogue: C-tile stride CP=136
// (measured 0-conflict), 8 b128 re-reads + 8 dwordx4 stores; fused es/ed.
#define GBM 128
#define GBN 128
#define GBK 64
#define CP  136   // C-tile LDS row stride (u16)

__global__ __launch_bounds__(256, 3) void mg_gemm(
    const u16* __restrict__ Ag, const u16* __restrict__ Bt,
    int Mstore, int Nn, int K,
    u16* __restrict__ Cb, const float* __restrict__ bias, int relu,
    const float* __restrict__ asrc, const float* __restrict__ adst,
    float* __restrict__ aes, float* __restrict__ aed) {
  __shared__ u16 lds[17408];   // 34.8 KB: staging A(8 KB u16)+B / C-tile union
  int tid = threadIdx.x;
  int n0 = blockIdx.x * GBN, m0 = blockIdx.y * GBM;
  int lane = tid & 63, wv = tid >> 6;
  int mw = (wv & 1) * 64, nw = (wv >> 1) * 64;
  int lr = lane & 15, lq = lane >> 4;
  int sr = lane & 7, scl = lane >> 3;        // staging: row-in-group, k-chunk

  f32x4 acc[4][4];
#pragma unroll
  for (int mi = 0; mi < 4; ++mi)
#pragma unroll
    for (int ni = 0; ni < 4; ++ni) acc[mi][ni] = (f32x4){0.f, 0.f, 0.f, 0.f};

  const u16* aB = Ag + (size_t)m0 * K + scl * 8;
  const u16* bB = Bt + (size_t)n0 * K + scl * 8;
  int niter = K >> 6;

  uint4 ra[4], rb[4];
#pragma unroll
  for (int j = 0; j < 4; ++j) {
    int grow = (wv * 4 + j) * 8 + sr;
    ra[j] = *(const uint4*)(aB + (size_t)grow * K);
    rb[j] = *(const uint4*)(bB + (size_t)grow * K);
  }

  for (int it = 0; it < niter; ++it) {
    __syncthreads();                 // previous compute done; LDS reusable
#pragma unroll
    for (int j = 0; j < 4; ++j) {    // ds_write waits on OWN loads (landed)
      int g = wv * 4 + j;
      *(uint4*)(lds + g * 512 + lane * 8) = ra[j];
      *(uint4*)(lds + 8192 + g * 512 + lane * 8) = rb[j];
    }
    if (it + 1 < niter) {            // issue next loads; no wait until next iter
      int k0 = (it + 1) * GBK;
#pragma unroll
      for (int j = 0; j < 4; ++j) {
        int grow = (wv * 4 + j) * 8 + sr;
        ra[j] = *(const uint4*)(aB + (size_t)grow * K + k0);
        rb[j] = *(const uint4*)(bB + (size_t)grow * K + k0);
      }
    }
    __syncthreads();                 // ds_writes visible (lgkm drain, fast)
#pragma unroll
    for (int kk = 0; kk < GBK; kk += 32) {
      int ca = (kk >> 3) + lq;
      short8 af[4], bfr[4];
#pragma unroll
      for (int mi = 0; mi < 4; ++mi) {
        int r = mw + mi * 16 + lr;
        af[mi] = *(const short8*)(lds + (r >> 3) * 512 + ca * 64 + (r & 7) * 8);
      }
#pragma unroll
      for (int ni = 0; ni < 4; ++ni) {
        int r = nw + ni * 16 + lr;
        bfr[ni] = *(const short8*)(lds + 8192 + (r >> 3) * 512 + ca * 64 + (r & 7) * 8);
      }
#pragma unroll
      for (int mi = 0; mi < 4; ++mi)
#pragma unroll
        for (int ni = 0; ni < 4; ++ni)
          acc[mi][ni] = __builtin_amdgcn_mfma_f32_16x16x32_bf16(af[mi], bfr[ni], acc[mi][ni], 0, 0, 0);
    }
  }
  __syncthreads();   // last compute done before C-tile overwrites staging LDS

  // ---- epilogue: acc -> LDS C-tile (bias/relu applied), then wide stores
  float bvv[4];
#pragma unroll
  for (int ni = 0; ni < 4; ++ni)
    bvv[ni] = bias ? bias[n0 + nw + ni * 16 + lr] : 0.f;

#pragma unroll
  for (int mi = 0; mi < 4; ++mi)
#pragma unroll
    for (int ni = 0; ni < 4; ++ni) {
      int cl = nw + ni * 16 + lr;
      int rb2 = mw + mi * 16 + lq * 4;
#pragma unroll
      for (int r = 0; r < 4; ++r) {
        float v = acc[mi][ni][r] + bvv[ni];
        if (relu) v = fmaxf(v, 0.f);
        lds[(rb2 + r) * CP + cl] = f2b(v);
      }
    }
  __syncthreads();

  int rowl = tid >> 1, half = (tid & 1) * 64;
  const u16* src = lds + rowl * CP + half;
  uint4 creg[8];
#pragma unroll
  for (int j = 0; j < 8; ++j) creg[j] = *(const uint4*)(src + j * 8);
  u16* gout = Cb + (size_t)(m0 + rowl) * Nn + n0 + half;
#pragma unroll
  for (int j = 0; j < 8; ++j) *(uint4*)(gout + j * 8) = creg[j];

  if (aes) {
    const float* ap = asrc + n0 + half;
    const float* dp = adst + n0 + half;
    float se = 0.f, de = 0.f;
#pragma unroll
    for (int j = 0; j < 8; ++j) {
      float4 a0 = *(const float4*)(ap + j * 8);
      float4 a1 = *(const float4*)(ap + j * 8 + 4);
      float4 d0 = *(const float4*)(dp + j * 8);
      float4 d1 = *(const float4*)(dp + j * 8 + 4);
      uint4 rv = creg[j];
      float v0 = bflo(rv.x), v1 = bfhi(rv.x), v2 = bflo(rv.y), v3 = bfhi(rv.y);
      float v4 = bflo(rv.z), v5 = bfhi(rv.z), v6 = bflo(rv.w), v7 = bfhi(rv.w);
      se += v0 * a0.x + v1 * a0.y + v2 * a0.z + v3 * a0.w
          + v4 * a1.x + v5 * a1.y + v6 * a1.z + v7 * a1.w;
      de += v0 * d0.x + v1 * d0.y + v2 * d0.z + v3 * d0.w
          + v4 * d1.x + v5 * d1.y + v6 * d1.z + v7 * d1.w;
    }
    se += __shfl_xor(se, 1);
    de += __shfl_xor(de, 1);
    int row = m0 + rowl;
    if ((tid & 1) == 0 && row < Mstore) {
      aes[row * 4 + blockIdx.x] = se;   // one writer per (row, head): plain store
      aed[row * 4 + blockIdx.x] = de;
    }
  }
}

// ---------------------------------------------------------------- GAT aggregate
// (round-8 version — best measured) 8 nodes/block, 2 per wave sequential.
// No max pass: softmax offset = self-loop edge score m = leaky(es[n]+ed[n]).
// Gather base scalarized via readfirstlane; depth-2 software pipeline.
// BN stats in registers -> LDS -> NSLICE slices.
__global__ __launch_bounds__(256) void mg_aggregate(
    const u16* __restrict__ B, const float* __restrict__ es,
    const float* __restrict__ ed, const int* __restrict__ rowptr,
    const int* __restrict__ colsrc, const float* __restrict__ bias,
    u16* __restrict__ A, float* __restrict__ stats) {
  __shared__ float bS[4 * W3D];
  __shared__ float bQ[4 * W3D];
  int wv = threadIdx.x >> 6, lane = threadIdx.x & 63;
  if (lane < 48) {
    int h = lane >> 4;
    int cc = lane * 8;
    float4 bv0 = *(const float4*)(bias + cc);
    float4 bv1 = *(const float4*)(bias + cc + 4);
    float stS[8], stQ[8];
#pragma unroll
    for (int j = 0; j < 8; ++j) { stS[j] = 0.f; stQ[j] = 0.f; }
#pragma unroll
    for (int sub = 0; sub < 2; ++sub) {
      int n = blockIdx.x * 8 + wv * 2 + sub;       // 12500*8 == NN exactly
      int r0 = rowptr[n], r1 = rowptr[n + 1];
      float4 edv = *(const float4*)(ed + 4 * n);
      float4 esn = *(const float4*)(es + 4 * n);
      float s0 = esn.x + edv.x; s0 = (s0 > 0.f) ? s0 : 0.2f * s0;
      float s1 = esn.y + edv.y; s1 = (s1 > 0.f) ? s1 : 0.2f * s1;
      float s2 = esn.z + edv.z; s2 = (s2 > 0.f) ? s2 : 0.2f * s2;
      float mh  = (h == 0) ? s0 : ((h == 1) ? s1 : s2);
      float edh = (h == 0) ? edv.x : ((h == 1) ? edv.y : edv.z);
      float accv[8];
#pragma unroll
      for (int j = 0; j < 8; ++j) accv[j] = 0.f;
      float ssum = 0.f;
      // depth-2 pipeline, scalar gather base
      int sA = __builtin_amdgcn_readfirstlane(colsrc[r0]);
      float4 evA = *(const float4*)(es + 4 * sA);
      uint4  rvA = *(const uint4*)(B + (size_t)sA * W3D + cc);
      float4 evB = evA; uint4 rvB = rvA;
      if (r0 + 1 < r1) {
        int sB = __builtin_amdgcn_readfirstlane(colsrc[r0 + 1]);
        evB = *(const float4*)(es + 4 * sB);
        rvB = *(const uint4*)(B + (size_t)sB * W3D + cc);
      }
      for (int r = r0; r < r1; ++r) {
        float4 ev = evA; uint4 rv = rvA;
        evA = evB; rvA = rvB;
        if (r + 2 < r1) {
          int sC = __builtin_amdgcn_readfirstlane(colsrc[r + 2]);
          evB = *(const float4*)(es + 4 * sC);
          rvB = *(const uint4*)(B + (size_t)sC * W3D + cc);
        }
        float e = ((h == 0) ? ev.x : ((h == 1) ? ev.y : ev.z)) + edh;
        e = (e > 0.f) ? e : 0.2f * e;
        float p = __expf(e - mh);
        ssum += p;
        accv[0] += p * bflo(rv.x); accv[1] += p * bfhi(rv.x);
        accv[2] += p * bflo(rv.y); accv[3] += p * bfhi(rv.y);
        accv[4] += p * bflo(rv.z); accv[5] += p * bfhi(rv.z);
        accv[6] += p * bflo(rv.w); accv[7] += p * bfhi(rv.w);
      }
      float inv = 1.0f / ssum;
      float v[8];
      v[0] = accv[0] * inv + bv0.x; v[1] = accv[1] * inv + bv0.y;
      v[2] = accv[2] * inv + bv0.z; v[3] = accv[3] * inv + bv0.w;
      v[4] = accv[4] * inv + bv1.x; v[5] = accv[5] * inv + bv1.y;
      v[6] = accv[6] * inv + bv1.z; v[7] = accv[7] * inv + bv1.w;
      uint4 st;
      st.x = (u32)f2b(v[0]) | ((u32)f2b(v[1]) << 16);
      st.y = (u32)f2b(v[2]) | ((u32)f2b(v[3]) << 16);
      st.z = (u32)f2b(v[4]) | ((u32)f2b(v[5]) << 16);
      st.w = (u32)f2b(v[6]) | ((u32)f2b(v[7]) << 16);
      *(uint4*)(A + (size_t)n * W3D + cc) = st;
#pragma unroll
      for (int j = 0; j < 8; ++j) { stS[j] += v[j]; stQ[j] += v[j] * v[j]; }
    }
    *(float4*)(bS + wv * W3D + cc)     = (float4){stS[0], stS[1], stS[2], stS[3]};
    *(float4*)(bS + wv * W3D + cc + 4) = (float4){stS[4], stS[5], stS[6], stS[7]};
    *(float4*)(bQ + wv * W3D + cc)     = (float4){stQ[0], stQ[1], stQ[2], stQ[3]};
    *(float4*)(bQ + wv * W3D + cc + 4) = (float4){stQ[4], stQ[5], stQ[6], stQ[7]};
  }
  __syncthreads();
  for (int t = threadIdx.x; t < W3D; t += 256) {
    float s = 0.f, q = 0.f;
#pragma unroll
    for (int w = 0; w < 4; ++w) { s += bS[w * W3D + t]; q += bQ[w * W3D + t]; }
    float* sl = stats + (size_t)(blockIdx.x & (NSLICE - 1)) * 768;
    atomicAdd(&sl[t], s);
    atomicAdd(&sl[W3D + t], q);
  }
}

// ---------------------------------------------------------------- BN finalize
__global__ void mg_bn_finalize(const float* __restrict__ stats, const float* __restrict__ gamma,
                               const float* __restrict__ beta, float* __restrict__ scale,
                               float* __restrict__ shift) {
  int c = threadIdx.x;   // 384 threads
  float s = 0.f, q = 0.f;
  for (int b = 0; b < NSLICE; ++b) { s += stats[b * 768 + c]; q += stats[b * 768 + W3D + c]; }
  const float invN = 1.0f / (float)NN;
  float mu = s * invN;
  float var = fmaxf(q * invN - mu * mu, 0.f);
  float inv = rsqrtf(var + 1e-5f);
  float g = gamma[c], be = beta[c];
  scale[c] = g * inv;
  shift[c] = be - mu * g * inv;
}

// ---------------------------------------------------------------- pool + head
__global__ void mg_pool(const u16* __restrict__ A, const float* __restrict__ scale,
                        const float* __restrict__ shift, const int* __restrict__ gptr,
                        float* __restrict__ pooled) {
  int g = blockIdx.x, c = threadIdx.x;   // 384 threads
  int r0 = gptr[g], r1 = gptr[g + 1];
  float acc = 0.f;
  for (int n = r0; n < r1; ++n) acc += bf2f(A[(size_t)n * W3D + c]);
  int cnt = r1 - r0;
  float v = (cnt > 0) ? (acc / (float)cnt) * scale[c] + shift[c] : 0.f;
  pooled[g * W3D + c] = v;
}

__global__ void mg_head(const float* __restrict__ pooled, const float* __restrict__ w3,
                        const float* __restrict__ b3, const float* __restrict__ w4,
                        const float* __restrict__ b4, float* __restrict__ out) {
  __shared__ float p[W3D];
  __shared__ float g2[HIDD];
  __shared__ float lg[NCLS];
  int g = blockIdx.x, t = threadIdx.x;   // 128 threads
  for (int i = t; i < W3D; i += 128) p[i] = pooled[g * W3D + i];
  __syncthreads();
  float acc = 0.f;
  for (int k = 0; k < W3D; ++k) acc += p[k] * w3[k * HIDD + t];
  g2[t] = fmaxf(acc + b3[t], 0.f);
  __syncthreads();
  if (t < NCLS) {
    float a = 0.f;
    for (int k = 0; k < HIDD; ++k) a += g2[k] * w4[k * NCLS + t];
    lg[t] = a + b4[t];
  }
  __syncthreads();
  if (t < NCLS) {
    float m = -1e30f;
#pragma unroll
    for (int j = 0; j < NCLS; ++j) m = fmaxf(m, lg[j]);
    float se = 0.f;
#pragma unroll
    for (int j = 0; j < NCLS; ++j) se += __expf(lg[j] - m);
    out[g * NCLS + t] = lg[t] - m - __logf(se);
  }
}

// ---------------------------------------------------------------- launch
extern "C" void kernel_launch(void* const* d_in, const int* in_sizes, int n_in,
                              void* d_out, int out_size, void* d_ws, size_t ws_size,
                              hipStream_t stream) {
  const float* x     = (const float*)d_in[0];
  const int*   ei    = (const int*)d_in[1];
  const int*   batch = (const int*)d_in[2];
  const float* w1    = (const float*)d_in[3];
  const float* b1    = (const float*)d_in[4];
  const float* w2    = (const float*)d_in[5];
  const float* b2    = (const float*)d_in[6];
  const float* w0    = (const float*)d_in[7];
  const float* as0   = (const float*)d_in[8];
  const float* ad0   = (const float*)d_in[9];
  const float* b0    = (const float*)d_in[10];
  const float* wl    = (const float*)d_in[11];
  const float* asl   = (const float*)d_in[12];
  const float* adl   = (const float*)d_in[13];
  const float* bl    = (const float*)d_in[14];
  const float* gamma = (const float*)d_in[15];
  const float* beta  = (const float*)d_in[16];
  const float* w3    = (const float*)d_in[17];
  const float* b3    = (const float*)d_in[18];
  const float* w4    = (const float*)d_in[19];
  const float* b4    = (const float*)d_in[20];
  float* out = (float*)d_out;

  char* w = (char*)d_ws;
  auto alloc = [&](size_t bytes) -> void* {
    void* p = (void*)w;
    w += (bytes + 255) & ~(size_t)255;
    return p;
  };
  u16*   P      = (u16*)alloc((size_t)NN2 * W3D * 2);  // gemm out / gather src
  u16*   Q      = (u16*)alloc((size_t)NN2 * W3D * 2);  // agg out / next gemm in
  float* es     = (float*)alloc((size_t)NN * 4 * 4);
  float* ed     = (float*)alloc((size_t)NN * 4 * 4);
  int*   deg    = (int*)alloc((size_t)NN * 4);
  int*   rowptr = (int*)alloc((size_t)(NN + 1) * 4);
  int*   fill   = (int*)alloc((size_t)NN * 4);
  int*   colsrc = (int*)alloc((size_t)ETOT * 4);
  int*   bsum   = (int*)alloc(256 * 4);
  float* stats  = (float*)alloc((size_t)NSLICE * 768 * 4);
  float* scale  = (float*)alloc(W3D * 4);
  float* shift  = (float*)alloc(W3D * 4);
  float* bprime = (float*)alloc(W3D * 4);
  int*   gptr   = (int*)alloc((size_t)(NG + 1) * 4);
  float* pooled = (float*)alloc((size_t)NG * W3D * 4);
  u16*   W1T    = (u16*)alloc(256 * 64 * 2);
  u16*   W2T    = (u16*)alloc(128 * 256 * 2);
  u16*   W0T    = (u16*)alloc(384 * 128 * 2);
  u16*   WlT    = (u16*)alloc((size_t)3 * 384 * 384 * 2);
  u16*   WpT    = (u16*)alloc((size_t)384 * 384 * 2);
  u16*   Xb     = Q;   // [NN2][64] bf16; Q is dead until stem2 writes it

  // Workspace too small -> clean zero output (diagnostic), no OOB
  if ((size_t)(w - (char*)d_ws) > ws_size) {
    mg_zero_out<<<(out_size + 255) / 256, 256, 0, stream>>>(out, out_size);
    return;
  }

  // input conversions
  mg_cvt_x<<<(NN2 * 64 + 255) / 256, 256, 0, stream>>>(x, Xb);
  mg_transpose_pad<<<(256 * 64 + 255) / 256, 256, 0, stream>>>(w1, W1T, 32, 256, 64);
  mg_transpose_pad<<<(128 * 256 + 255) / 256, 256, 0, stream>>>(w2, W2T, 256, 128, 256);
  mg_transpose_pad<<<(384 * 128 + 255) / 256, 256, 0, stream>>>(w0, W0T, 128, 384, 128);
  for (int i = 0; i < 3; ++i)
    mg_transpose_pad<<<(384 * 384 + 255) / 256, 256, 0, stream>>>(
        wl + (size_t)i * 384 * 384, WlT + (size_t)i * 384 * 384, 384, 384, 384);

  // CSR by dst (built once, reused by all 4 layers)
  hipMemsetAsync(deg, 0, (size_t)NN * 4, stream);
  mg_edge_histo<<<(ETOT + 255) / 256, 256, 0, stream>>>(ei, deg);
  int nb = (NN + 1023) / 1024;   // 98
  mg_scan1<<<nb, 256, 0, stream>>>(deg, bsum, NN);
  mg_scan2<<<1, 256, 0, stream>>>(bsum, nb);
  mg_scan3<<<nb, 256, 0, stream>>>(deg, bsum, rowptr, NN);
  hipMemcpyAsync(fill, rowptr, (size_t)NN * 4, hipMemcpyDeviceToDevice, stream);
  mg_edge_scatter<<<(ETOT + 255) / 256, 256, 0, stream>>>(ei, fill, colsrc);
  mg_graph_ptr<<<(NG + 1 + 255) / 256, 256, 0, stream>>>(batch, gptr);

  dim3 blk(256);
  int mtiles = NN2 / GBM;   // 782

  // stem: relu(x@W1+b1) -> relu(@W2+b2); P: [NN2][256], then Q: [NN2][128]
  mg_gemm<<<dim3(2, mtiles), blk, 0, stream>>>(Xb, W1T, NN, 256, 64,
                                               P, b1, 1,
                                               nullptr, nullptr, nullptr, nullptr);
  mg_gemm<<<dim3(1, mtiles), blk, 0, stream>>>(P, W2T, NN, 128, 256,
                                               Q, b2, 1,
                                               nullptr, nullptr, nullptr, nullptr);

  for (int i = 0; i < 4; ++i) {
    int K = (i == 0) ? 128 : 384;
    const u16* Bt;
    const float* bi_g = nullptr;   // GEMM bias (folded BN shift term)
    if (i == 0) {
      Bt = W0T;
    } else {
      // fold BN of previous layer into this layer's weights + bias
      mg_fold_w<<<384, 128, 0, stream>>>(WlT + (size_t)(i - 1) * 384 * 384,
                                         scale, shift, WpT, bprime);
      Bt = WpT;
      bi_g = bprime;
    }
    const float* as = (i == 0) ? as0 : (asl + (size_t)(i - 1) * 384);
    const float* ad = (i == 0) ? ad0 : (adl + (size_t)(i - 1) * 384);
    const float* bi = (i == 0) ? b0  : (bl  + (size_t)(i - 1) * 384);
    hipMemsetAsync(stats, 0, (size_t)NSLICE * 768 * 4, stream);
    mg_gemm<<<dim3(3, mtiles), blk, 0, stream>>>(Q, Bt, NN, W3D, K,
                                                 P, bi_g, 0,
                                                 as, ad, es, ed);
    mg_aggregate<<<NN / 8, 256, 0, stream>>>(P, es, ed, rowptr, colsrc, bi, Q, stats);
    mg_bn_finalize<<<1, 384, 0, stream>>>(stats, gamma + (size_t)i * W3D,
                                          beta + (size_t)i * W3D, scale, shift);
  }

  // global mean pool (BN3 folded in) + MLP head + log_softmax
  mg_pool<<<NG, 384, 0, stream>>>(Q, scale, shift, gptr, pooled);
  mg_head<<<NG, 128, 0, stream>>>(pooled, w3, b3, w4, b4, out);
}

// Round 12
// 1292.488 us; speedup vs baseline: 1.1830x; 1.1830x over previous
//
#include <hip/hip_runtime.h>

#define NN      100000      // nodes
#define NN2     100096      // nodes padded to 128 (782 tiles)
#define NE      400000      // raw edges
#define ETOT    500000      // edges + self loops
#define NG      4000        // graphs
#define W3D     384
#define HIDD    128
#define NCLS    10
#define NSLICE  256         // stat accumulation slices

typedef unsigned short u16;
typedef unsigned int   u32;
typedef unsigned long long u64;
typedef __attribute__((ext_vector_type(8))) short short8;
typedef __attribute__((ext_vector_type(4))) float f32x4;

static __device__ __forceinline__ float bf2f(u16 u) {
  return __uint_as_float(((u32)u) << 16);
}
static __device__ __forceinline__ float bflo(u32 u) {
  return __uint_as_float(u << 16);
}
static __device__ __forceinline__ float bfhi(u32 u) {
  return __uint_as_float(u & 0xffff0000u);
}
static __device__ __forceinline__ u16 f2b(float f) {
  u32 u = __float_as_uint(f);
  u32 r = (u + 0x7fffu + ((u >> 16) & 1u)) >> 16;
  return (u16)r;
}

// async global->LDS, 16 B per lane; LDS dest = wave-uniform base + lane*16
static __device__ __forceinline__ void llds16(const u16* g, u16* l) {
  __builtin_amdgcn_global_load_lds(
      (const __attribute__((address_space(1))) void*)(u64)(const void*)g,
      (__attribute__((address_space(3))) void*)(u64)(void*)l, 16, 0, 0);
}

// ---------------------------------------------------------------- fallback
__global__ void mg_zero_out(float* out, int n) {
  int i = blockIdx.x * 256 + threadIdx.x;
  if (i < n) out[i] = 0.f;
}

// ---------------------------------------------------------------- x -> bf16 [NN2][64] zero-padded
__global__ void mg_cvt_x(const float* __restrict__ x, u16* __restrict__ Xb) {
  int idx = blockIdx.x * 256 + threadIdx.x;
  if (idx >= NN2 * 64) return;
  int row = idx >> 6, col = idx & 63;
  Xb[idx] = (row < NN && col < 32) ? f2b(x[row * 32 + col]) : (u16)0;
}

// ---------------------------------------------------------------- transpose
// out[n][k] = bf16(in[k][n]), zero-padded to Kpad. in is fp32.
__global__ void mg_transpose_pad(const float* __restrict__ in, u16* __restrict__ out,
                                 int K, int Nn, int Kpad) {
  int idx = blockIdx.x * 256 + threadIdx.x;
  if (idx >= Nn * Kpad) return;
  int n = idx / Kpad, k = idx - n * Kpad;
  out[idx] = (k < K) ? f2b(in[k * Nn + n]) : (u16)0;
}

// ---------------------------------------------------------------- BN -> weight fold
// Wp[j][k] = Wt[j][k]*scale[k];  bp[j] = sum_k shift[k]*Wt[j][k]
__global__ void mg_fold_w(const u16* __restrict__ Wt, const float* __restrict__ scale,
                          const float* __restrict__ shift, u16* __restrict__ Wp,
                          float* __restrict__ bp) {
  __shared__ float red[128];
  int j = blockIdx.x, t = threadIdx.x;   // 384 blocks x 128 threads
  const u16* src = Wt + (size_t)j * W3D;
  u16* dst = Wp + (size_t)j * W3D;
  float acc = 0.f;
  for (int k = t; k < W3D; k += 128) {
    float w = bf2f(src[k]);
    dst[k] = f2b(w * scale[k]);
    acc += w * shift[k];
  }
  red[t] = acc; __syncthreads();
  for (int off = 64; off; off >>= 1) {
    if (t < off) red[t] += red[t + off];
    __syncthreads();
  }
  if (t == 0) bp[j] = red[0];
}

// ---------------------------------------------------------------- CSR build
__global__ void mg_edge_histo(const int* __restrict__ ei, int* __restrict__ deg) {
  int e = blockIdx.x * 256 + threadIdx.x;
  if (e >= ETOT) return;
  int d = (e < NE) ? ei[NE + e] : (e - NE);
  atomicAdd(&deg[d], 1);
}

__global__ void mg_scan1(const int* __restrict__ in, int* __restrict__ bsum, int n) {
  __shared__ int sd[256];
  int tid = threadIdx.x;
  int base = blockIdx.x * 1024 + tid * 4;
  int s = 0;
#pragma unroll
  for (int j = 0; j < 4; ++j) { int i = base + j; if (i < n) s += in[i]; }
  sd[tid] = s; __syncthreads();
  for (int off = 128; off > 0; off >>= 1) {
    if (tid < off) sd[tid] += sd[tid + off];
    __syncthreads();
  }
  if (tid == 0) bsum[blockIdx.x] = sd[0];
}

__global__ void mg_scan2(int* __restrict__ bsum, int nb) {
  __shared__ int sd[256];
  int tid = threadIdx.x;
  int v = (tid < nb) ? bsum[tid] : 0;
  sd[tid] = v; __syncthreads();
  for (int off = 1; off < 256; off <<= 1) {
    int t = (tid >= off) ? sd[tid - off] : 0;
    __syncthreads();
    sd[tid] += t;
    __syncthreads();
  }
  if (tid < nb) bsum[tid] = sd[tid] - v;   // exclusive
}

__global__ void mg_scan3(const int* __restrict__ in, const int* __restrict__ bexcl,
                         int* __restrict__ out, int n) {
  __shared__ int sd[256];
  int tid = threadIdx.x;
  int base = blockIdx.x * 1024 + tid * 4;
  int loc[4]; int s = 0;
#pragma unroll
  for (int j = 0; j < 4; ++j) { int i = base + j; loc[j] = (i < n) ? in[i] : 0; s += loc[j]; }
  sd[tid] = s; __syncthreads();
  for (int off = 1; off < 256; off <<= 1) {
    int t = (tid >= off) ? sd[tid - off] : 0;
    __syncthreads();
    sd[tid] += t;
    __syncthreads();
  }
  int run = sd[tid] - s + bexcl[blockIdx.x];
#pragma unroll
  for (int j = 0; j < 4; ++j) {
    int i = base + j;
    if (i < n) { out[i] = run; run += loc[j]; if (i == n - 1) out[n] = run; }
  }
}

__global__ void mg_edge_scatter(const int* __restrict__ ei, int* __restrict__ fill,
                                int* __restrict__ colsrc) {
  int e = blockIdx.x * 256 + threadIdx.x;
  if (e >= ETOT) return;
  int s, d;
  if (e < NE) { s = ei[e]; d = ei[NE + e]; } else { s = e - NE; d = s; }
  int pos = atomicAdd(&fill[d], 1);
  colsrc[pos] = s;
}

__global__ void mg_graph_ptr(const int* __restrict__ batch, int* __restrict__ gptr) {
  int g = blockIdx.x * 256 + threadIdx.x;
  if (g > NG) return;
  if (g == NG) { gptr[NG] = NN; return; }
  int lo = 0, hi = NN;
  while (lo < hi) { int mid = (lo + hi) >> 1; if (batch[mid] < g) lo = mid + 1; else hi = mid; }
  gptr[g] = lo;
}

// ---------------------------------------------------------------- GEMM (bf16 MFMA)
// (round-9 version, known-good ~108 us) C = A @ B; A bf16 [NN2][K], Bt [Nn][K].
// GBK=32, single barrier per K-iter via llds16 double buffer.
#define GBM 128
#define GBN 128
#define GBK 32
#define CP  130   // C-tile LDS row stride (u16)

__global__ __launch_bounds__(256) void mg_gemm(
    const u16* __restrict__ Ag, const u16* __restrict__ Bt,
    int Mstore, int Nn, int K,
    u16* __restrict__ Cb, const float* __restrict__ bias, int relu,
    const float* __restrict__ asrc, const float* __restrict__ adst,
    float* __restrict__ aes, float* __restrict__ aed) {
  __shared__ u16 lds[17408];   // 34.8 KB: staging A0 A1 B0 B1 (8 KB each) / C-tile
  int tid = threadIdx.x;
  int n0 = blockIdx.x * GBN, m0 = blockIdx.y * GBM;
  int lane = tid & 63, wv = tid >> 6;
  int mw = (wv & 1) * 64, nw = (wv >> 1) * 64;
  int lr = lane & 15, lq = lane >> 4;
  int rr = lane & 15, cc4 = lane >> 4;       // staging: row-in-supergroup, k-chunk

  f32x4 acc[4][4];
#pragma unroll
  for (int mi = 0; mi < 4; ++mi)
#pragma unroll
    for (int ni = 0; ni < 4; ++ni) acc[mi][ni] = (f32x4){0.f, 0.f, 0.f, 0.f};

  const u16* aB = Ag + (size_t)m0 * K + cc4 * 8;
  const u16* bB = Bt + (size_t)n0 * K + cc4 * 8;
  int niter = K >> 5;

  // stage iteration 0 into buffer 0
#pragma unroll
  for (int j = 0; j < 2; ++j) {
    int sg = wv * 2 + j, grow = sg * 16 + rr;
    llds16(aB + (size_t)grow * K, lds + sg * 512);
    llds16(bB + (size_t)grow * K, lds + 8192 + sg * 512);
  }

  for (int it = 0; it < niter; ++it) {
    __syncthreads();                         // drains stage(it); guards buf reuse
    if (it + 1 < niter) {
      int k0 = (it + 1) * GBK, b = (it + 1) & 1;
#pragma unroll
      for (int j = 0; j < 2; ++j) {
        int sg = wv * 2 + j, grow = sg * 16 + rr;
        llds16(aB + (size_t)grow * K + k0, lds + b * 4096 + sg * 512);
        llds16(bB + (size_t)grow * K + k0, lds + 8192 + b * 4096 + sg * 512);
      }
    }
    const u16* Al = lds + (it & 1) * 4096;
    const u16* Bl = lds + 8192 + (it & 1) * 4096;
    short8 af[4], bfr[4];
#pragma unroll
    for (int mi = 0; mi < 4; ++mi)
      af[mi] = *(const short8*)(Al + ((mw >> 4) + mi) * 512 + lq * 128 + lr * 8);
#pragma unroll
    for (int ni = 0; ni < 4; ++ni)
      bfr[ni] = *(const short8*)(Bl + ((nw >> 4) + ni) * 512 + lq * 128 + lr * 8);
#pragma unroll
    for (int mi = 0; mi < 4; ++mi)
#pragma unroll
      for (int ni = 0; ni < 4; ++ni)
        acc[mi][ni] = __builtin_amdgcn_mfma_f32_16x16x32_bf16(af[mi], bfr[ni], acc[mi][ni], 0, 0, 0);
  }
  __syncthreads();   // all waves done with staging buffers before C-tile reuse

  // ---- epilogue: acc -> LDS C-tile (bias/relu applied), then wide stores
  float bvv[4];
#pragma unroll
  for (int ni = 0; ni < 4; ++ni)
    bvv[ni] = bias ? bias[n0 + nw + ni * 16 + lr] : 0.f;

#pragma unroll
  for (int mi = 0; mi < 4; ++mi)
#pragma unroll
    for (int ni = 0; ni < 4; ++ni) {
      int cl = nw + ni * 16 + lr;
      int rb = mw + mi * 16 + lq * 4;
#pragma unroll
      for (int r = 0; r < 4; ++r) {
        float v = acc[mi][ni][r] + bvv[ni];
        if (relu) v = fmaxf(v, 0.f);
        lds[(rb + r) * CP + cl] = f2b(v);
      }
    }
  __syncthreads();

  int rowl = tid >> 1, half = (tid & 1) * 64;
  const u16* src = lds + rowl * CP + half;
  uint4 creg[8];
#pragma unroll
  for (int j = 0; j < 8; ++j) creg[j] = *(const uint4*)(src + j * 8);
  u16* gout = Cb + (size_t)(m0 + rowl) * Nn + n0 + half;
#pragma unroll
  for (int j = 0; j < 8; ++j) *(uint4*)(gout + j * 8) = creg[j];

  if (aes) {
    const float* ap = asrc + n0 + half;
    const float* dp = adst + n0 + half;
    float se = 0.f, de = 0.f;
#pragma unroll
    for (int j = 0; j < 8; ++j) {
      float4 a0 = *(const float4*)(ap + j * 8);
      float4 a1 = *(const float4*)(ap + j * 8 + 4);
      float4 d0 = *(const float4*)(dp + j * 8);
      float4 d1 = *(const float4*)(dp + j * 8 + 4);
      uint4 rv = creg[j];
      float v0 = bflo(rv.x), v1 = bfhi(rv.x), v2 = bflo(rv.y), v3 = bfhi(rv.y);
      float v4 = bflo(rv.z), v5 = bfhi(rv.z), v6 = bflo(rv.w), v7 = bfhi(rv.w);
      se += v0 * a0.x + v1 * a0.y + v2 * a0.z + v3 * a0.w
          + v4 * a1.x + v5 * a1.y + v6 * a1.z + v7 * a1.w;
      de += v0 * d0.x + v1 * d0.y + v2 * d0.z + v3 * d0.w
          + v4 * d1.x + v5 * d1.y + v6 * d1.z + v7 * d1.w;
    }
    se += __shfl_xor(se, 1);
    de += __shfl_xor(de, 1);
    int row = m0 + rowl;
    if ((tid & 1) == 0 && row < Mstore) {
      aes[row * 4 + blockIdx.x] = se;   // one writer per (row, head): plain store
      aed[row * 4 + blockIdx.x] = de;
    }
  }
}

// ---------------------------------------------------------------- GAT aggregate
// 8 nodes/block, 2 per wave sequential. No max pass (self-loop offset).
// DEPTH-4 software pipeline: 4 statically-indexed slots, edge loop unrolled
// by 4 (no register rotation — round-10 lesson), wave-uniform guards.
// Gather base scalarized via readfirstlane. BN stats regs -> LDS -> slices.
#define AG_LOAD(EV, RV, IDX)                                          \
  { int s_ = __builtin_amdgcn_readfirstlane(colsrc[IDX]);             \
    EV = *(const float4*)(es + 4 * s_);                               \
    RV = *(const uint4*)(B + (size_t)s_ * W3D + cc); }
#define AG_CONSUME(EV, RV)                                            \
  { float e_ = ((h == 0) ? EV.x : ((h == 1) ? EV.y : EV.z)) + edh;    \
    e_ = (e_ > 0.f) ? e_ : 0.2f * e_;                                 \
    float p_ = __expf(e_ - mh);                                       \
    ssum += p_;                                                       \
    accv[0] += p_ * bflo(RV.x); accv[1] += p_ * bfhi(RV.x);           \
    accv[2] += p_ * bflo(RV.y); accv[3] += p_ * bfhi(RV.y);           \
    accv[4] += p_ * bflo(RV.z); accv[5] += p_ * bfhi(RV.z);           \
    accv[6] += p_ * bflo(RV.w); accv[7] += p_ * bfhi(RV.w); }

__global__ __launch_bounds__(256) void mg_aggregate(
    const u16* __restrict__ B, const float* __restrict__ es,
    const float* __restrict__ ed, const int* __restrict__ rowptr,
    const int* __restrict__ colsrc, const float* __restrict__ bias,
    u16* __restrict__ A, float* __restrict__ stats) {
  __shared__ float bS[4 * W3D];
  __shared__ float bQ[4 * W3D];
  int wv = threadIdx.x >> 6, lane = threadIdx.x & 63;
  if (lane < 48) {
    int h = lane >> 4;
    int cc = lane * 8;
    float4 bv0 = *(const float4*)(bias + cc);
    float4 bv1 = *(const float4*)(bias + cc + 4);
    float stS[8], stQ[8];
#pragma unroll
    for (int j = 0; j < 8; ++j) { stS[j] = 0.f; stQ[j] = 0.f; }
#pragma unroll
    for (int sub = 0; sub < 2; ++sub) {
      int n = blockIdx.x * 8 + wv * 2 + sub;       // 12500*8 == NN exactly
      int r0 = rowptr[n], r1 = rowptr[n + 1];
      float4 edv = *(const float4*)(ed + 4 * n);
      float4 esn = *(const float4*)(es + 4 * n);
      float s0 = esn.x + edv.x; s0 = (s0 > 0.f) ? s0 : 0.2f * s0;
      float s1 = esn.y + edv.y; s1 = (s1 > 0.f) ? s1 : 0.2f * s1;
      float s2 = esn.z + edv.z; s2 = (s2 > 0.f) ? s2 : 0.2f * s2;
      float mh  = (h == 0) ? s0 : ((h == 1) ? s1 : s2);
      float edh = (h == 0) ? edv.x : ((h == 1) ? edv.y : edv.z);
      float accv[8];
#pragma unroll
      for (int j = 0; j < 8; ++j) accv[j] = 0.f;
      float ssum = 0.f;
      // ---- depth-4 pipeline: prologue (guarded)
      float4 ev0, ev1, ev2, ev3; uint4 rv0, rv1, rv2, rv3;
      AG_LOAD(ev0, rv0, r0);                       // self-loop guarantees r1>r0
      if (r0 + 1 < r1) AG_LOAD(ev1, rv1, r0 + 1);
      if (r0 + 2 < r1) AG_LOAD(ev2, rv2, r0 + 2);
      if (r0 + 3 < r1) AG_LOAD(ev3, rv3, r0 + 3);
      // ---- full groups of 4
      int r = r0;
      for (; r + 4 <= r1; r += 4) {
        AG_CONSUME(ev0, rv0); if (r + 4 < r1) AG_LOAD(ev0, rv0, r + 4);
        AG_CONSUME(ev1, rv1); if (r + 5 < r1) AG_LOAD(ev1, rv1, r + 5);
        AG_CONSUME(ev2, rv2); if (r + 6 < r1) AG_LOAD(ev2, rv2, r + 6);
        AG_CONSUME(ev3, rv3); if (r + 7 < r1) AG_LOAD(ev3, rv3, r + 7);
      }
      // ---- tail (0..3 edges, held in slots 0..rem-1)
      int rem = r1 - r;
      if (rem > 0) AG_CONSUME(ev0, rv0);
      if (rem > 1) AG_CONSUME(ev1, rv1);
      if (rem > 2) AG_CONSUME(ev2, rv2);

      float inv = 1.0f / ssum;
      float v[8];
      v[0] = accv[0] * inv + bv0.x; v[1] = accv[1] * inv + bv0.y;
      v[2] = accv[2] * inv + bv0.z; v[3] = accv[3] * inv + bv0.w;
      v[4] = accv[4] * inv + bv1.x; v[5] = accv[5] * inv + bv1.y;
      v[6] = accv[6] * inv + bv1.z; v[7] = accv[7] * inv + bv1.w;
      uint4 st;
      st.x = (u32)f2b(v[0]) | ((u32)f2b(v[1]) << 16);
      st.y = (u32)f2b(v[2]) | ((u32)f2b(v[3]) << 16);
      st.z = (u32)f2b(v[4]) | ((u32)f2b(v[5]) << 16);
      st.w = (u32)f2b(v[6]) | ((u32)f2b(v[7]) << 16);
      *(uint4*)(A + (size_t)n * W3D + cc) = st;
#pragma unroll
      for (int j = 0; j < 8; ++j) { stS[j] += v[j]; stQ[j] += v[j] * v[j]; }
    }
    *(float4*)(bS + wv * W3D + cc)     = (float4){stS[0], stS[1], stS[2], stS[3]};
    *(float4*)(bS + wv * W3D + cc + 4) = (float4){stS[4], stS[5], stS[6], stS[7]};
    *(float4*)(bQ + wv * W3D + cc)     = (float4){stQ[0], stQ[1], stQ[2], stQ[3]};
    *(float4*)(bQ + wv * W3D + cc + 4) = (float4){stQ[4], stQ[5], stQ[6], stQ[7]};
  }
  __syncthreads();
  for (int t = threadIdx.x; t < W3D; t += 256) {
    float s = 0.f, q = 0.f;
#pragma unroll
    for (int w = 0; w < 4; ++w) { s += bS[w * W3D + t]; q += bQ[w * W3D + t]; }
    float* sl = stats + (size_t)(blockIdx.x & (NSLICE - 1)) * 768;
    atomicAdd(&sl[t], s);
    atomicAdd(&sl[W3D + t], q);
  }
}

// ---------------------------------------------------------------- BN finalize
__global__ void mg_bn_finalize(const float* __restrict__ stats, const float* __restrict__ gamma,
                               const float* __restrict__ beta, float* __restrict__ scale,
                               float* __restrict__ shift) {
  int c = threadIdx.x;   // 384 threads
  float s = 0.f, q = 0.f;
  for (int b = 0; b < NSLICE; ++b) { s += stats[b * 768 + c]; q += stats[b * 768 + W3D + c]; }
  const float invN = 1.0f / (float)NN;
  float mu = s * invN;
  float var = fmaxf(q * invN - mu * mu, 0.f);
  float inv = rsqrtf(var + 1e-5f);
  float g = gamma[c], be = beta[c];
  scale[c] = g * inv;
  shift[c] = be - mu * g * inv;
}

// ---------------------------------------------------------------- pool + head
__global__ void mg_pool(const u16* __restrict__ A, const float* __restrict__ scale,
                        const float* __restrict__ shift, const int* __restrict__ gptr,
                        float* __restrict__ pooled) {
  int g = blockIdx.x, c = threadIdx.x;   // 384 threads
  int r0 = gptr[g], r1 = gptr[g + 1];
  float acc = 0.f;
  for (int n = r0; n < r1; ++n) acc += bf2f(A[(size_t)n * W3D + c]);
  int cnt = r1 - r0;
  float v = (cnt > 0) ? (acc / (float)cnt) * scale[c] + shift[c] : 0.f;
  pooled[g * W3D + c] = v;
}

__global__ void mg_head(const float* __restrict__ pooled, const float* __restrict__ w3,
                        const float* __restrict__ b3, const float* __restrict__ w4,
                        const float* __restrict__ b4, float* __restrict__ out) {
  __shared__ float p[W3D];
  __shared__ float g2[HIDD];
  __shared__ float lg[NCLS];
  int g = blockIdx.x, t = threadIdx.x;   // 128 threads
  for (int i = t; i < W3D; i += 128) p[i] = pooled[g * W3D + i];
  __syncthreads();
  float acc = 0.f;
  for (int k = 0; k < W3D; ++k) acc += p[k] * w3[k * HIDD + t];
  g2[t] = fmaxf(acc + b3[t], 0.f);
  __syncthreads();
  if (t < NCLS) {
    float a = 0.f;
    for (int k = 0; k < HIDD; ++k) a += g2[k] * w4[k * NCLS + t];
    lg[t] = a + b4[t];
  }
  __syncthreads();
  if (t < NCLS) {
    float m = -1e30f;
#pragma unroll
    for (int j = 0; j < NCLS; ++j) m = fmaxf(m, lg[j]);
    float se = 0.f;
#pragma unroll
    for (int j = 0; j < NCLS; ++j) se += __expf(lg[j] - m);
    out[g * NCLS + t] = lg[t] - m - __logf(se);
  }
}

// ---------------------------------------------------------------- launch
extern "C" void kernel_launch(void* const* d_in, const int* in_sizes, int n_in,
                              void* d_out, int out_size, void* d_ws, size_t ws_size,
                              hipStream_t stream) {
  const float* x     = (const float*)d_in[0];
  const int*   ei    = (const int*)d_in[1];
  const int*   batch = (const int*)d_in[2];
  const float* w1    = (const float*)d_in[3];
  const float* b1    = (const float*)d_in[4];
  const float* w2    = (const float*)d_in[5];
  const float* b2    = (const float*)d_in[6];
  const float* w0    = (const float*)d_in[7];
  const float* as0   = (const float*)d_in[8];
  const float* ad0   = (const float*)d_in[9];
  const float* b0    = (const float*)d_in[10];
  const float* wl    = (const float*)d_in[11];
  const float* asl   = (const float*)d_in[12];
  const float* adl   = (const float*)d_in[13];
  const float* bl    = (const float*)d_in[14];
  const float* gamma = (const float*)d_in[15];
  const float* beta  = (const float*)d_in[16];
  const float* w3    = (const float*)d_in[17];
  const float* b3    = (const float*)d_in[18];
  const float* w4    = (const float*)d_in[19];
  const float* b4    = (const float*)d_in[20];
  float* out = (float*)d_out;

  char* w = (char*)d_ws;
  auto alloc = [&](size_t bytes) -> void* {
    void* p = (void*)w;
    w += (bytes + 255) & ~(size_t)255;
    return p;
  };
  u16*   P      = (u16*)alloc((size_t)NN2 * W3D * 2);  // gemm out / gather src
  u16*   Q      = (u16*)alloc((size_t)NN2 * W3D * 2);  // agg out / next gemm in
  float* es     = (float*)alloc((size_t)NN * 4 * 4);
  float* ed     = (float*)alloc((size_t)NN * 4 * 4);
  int*   deg    = (int*)alloc((size_t)NN * 4);
  int*   rowptr = (int*)alloc((size_t)(NN + 1) * 4);
  int*   fill   = (int*)alloc((size_t)NN * 4);
  int*   colsrc = (int*)alloc((size_t)ETOT * 4);
  int*   bsum   = (int*)alloc(256 * 4);
  float* stats  = (float*)alloc((size_t)NSLICE * 768 * 4);
  float* scale  = (float*)alloc(W3D * 4);
  float* shift  = (float*)alloc(W3D * 4);
  float* bprime = (float*)alloc(W3D * 4);
  int*   gptr   = (int*)alloc((size_t)(NG + 1) * 4);
  float* pooled = (float*)alloc((size_t)NG * W3D * 4);
  u16*   W1T    = (u16*)alloc(256 * 64 * 2);
  u16*   W2T    = (u16*)alloc(128 * 256 * 2);
  u16*   W0T    = (u16*)alloc(384 * 128 * 2);
  u16*   WlT    = (u16*)alloc((size_t)3 * 384 * 384 * 2);
  u16*   WpT    = (u16*)alloc((size_t)384 * 384 * 2);
  u16*   Xb     = Q;   // [NN2][64] bf16; Q is dead until stem2 writes it

  // Workspace too small -> clean zero output (diagnostic), no OOB
  if ((size_t)(w - (char*)d_ws) > ws_size) {
    mg_zero_out<<<(out_size + 255) / 256, 256, 0, stream>>>(out, out_size);
    return;
  }

  // input conversions
  mg_cvt_x<<<(NN2 * 64 + 255) / 256, 256, 0, stream>>>(x, Xb);
  mg_transpose_pad<<<(256 * 64 + 255) / 256, 256, 0, stream>>>(w1, W1T, 32, 256, 64);
  mg_transpose_pad<<<(128 * 256 + 255) / 256, 256, 0, stream>>>(w2, W2T, 256, 128, 256);
  mg_transpose_pad<<<(384 * 128 + 255) / 256, 256, 0, stream>>>(w0, W0T, 128, 384, 128);
  for (int i = 0; i < 3; ++i)
    mg_transpose_pad<<<(384 * 384 + 255) / 256, 256, 0, stream>>>(
        wl + (size_t)i * 384 * 384, WlT + (size_t)i * 384 * 384, 384, 384, 384);

  // CSR by dst (built once, reused by all 4 layers)
  hipMemsetAsync(deg, 0, (size_t)NN * 4, stream);
  mg_edge_histo<<<(ETOT + 255) / 256, 256, 0, stream>>>(ei, deg);
  int nb = (NN + 1023) / 1024;   // 98
  mg_scan1<<<nb, 256, 0, stream>>>(deg, bsum, NN);
  mg_scan2<<<1, 256, 0, stream>>>(bsum, nb);
  mg_scan3<<<nb, 256, 0, stream>>>(deg, bsum, rowptr, NN);
  hipMemcpyAsync(fill, rowptr, (size_t)NN * 4, hipMemcpyDeviceToDevice, stream);
  mg_edge_scatter<<<(ETOT + 255) / 256, 256, 0, stream>>>(ei, fill, colsrc);
  mg_graph_ptr<<<(NG + 1 + 255) / 256, 256, 0, stream>>>(batch, gptr);

  dim3 blk(256);
  int mtiles = NN2 / GBM;   // 782

  // stem: relu(x@W1+b1) -> relu(@W2+b2); P: [NN2][256], then Q: [NN2][128]
  mg_gemm<<<dim3(2, mtiles), blk, 0, stream>>>(Xb, W1T, NN, 256, 64,
                                               P, b1, 1,
                                               nullptr, nullptr, nullptr, nullptr);
  mg_gemm<<<dim3(1, mtiles), blk, 0, stream>>>(P, W2T, NN, 128, 256,
                                               Q, b2, 1,
                                               nullptr, nullptr, nullptr, nullptr);

  for (int i = 0; i < 4; ++i) {
    int K = (i == 0) ? 128 : 384;
    const u16* Bt;
    const float* bi_g = nullptr;   // GEMM bias (folded BN shift term)
    if (i == 0) {
      Bt = W0T;
    } else {
      // fold BN of previous layer into this layer's weights + bias
      mg_fold_w<<<384, 128, 0, stream>>>(WlT + (size_t)(i - 1) * 384 * 384,
                                         scale, shift, WpT, bprime);
      Bt = WpT;
      bi_g = bprime;
    }
    const float* as = (i == 0) ? as0 : (asl + (size_t)(i - 1) * 384);
    const float* ad = (i == 0) ? ad0 : (adl + (size_t)(i - 1) * 384);
    const float* bi = (i == 0) ? b0  : (bl  + (size_t)(i - 1) * 384);
    hipMemsetAsync(stats, 0, (size_t)NSLICE * 768 * 4, stream);
    mg_gemm<<<dim3(3, mtiles), blk, 0, stream>>>(Q, Bt, NN, W3D, K,
                                                 P, bi_g, 0,
                                                 as, ad, es, ed);
    mg_aggregate<<<NN / 8, 256, 0, stream>>>(P, es, ed, rowptr, colsrc, bi, Q, stats);
    mg_bn_finalize<<<1, 384, 0, stream>>>(stats, gamma + (size_t)i * W3D,
                                          beta + (size_t)i * W3D, scale, shift);
  }

  // global mean pool (BN3 folded in) + MLP head + log_softmax
  mg_pool<<<NG, 384, 0, stream>>>(Q, scale, shift, gptr, pooled);
  mg_head<<<NG, 128, 0, stream>>>(pooled, w3, b3, w4, b4, out);
}

// Round 13
// 1109.126 us; speedup vs baseline: 1.3786x; 1.1653x over previous
//
#include <hip/hip_runtime.h>

#define NN      100000      // nodes
#define NN2     100096      // nodes padded to 128 (782 tiles)
#define NE      400000      // raw edges
#define ETOT    500000      // edges + self loops
#define NG      4000        // graphs
#define W3D     384
#define HIDD    128
#define NCLS    10
#define NSLICE  256         // stat accumulation slices

typedef unsigned short u16;
typedef unsigned int   u32;
typedef unsigned long long u64;
typedef __attribute__((ext_vector_type(8))) short short8;
typedef __attribute__((ext_vector_type(4))) float f32x4;

static __device__ __forceinline__ float bf2f(u16 u) {
  return __uint_as_float(((u32)u) << 16);
}
static __device__ __forceinline__ float bflo(u32 u) {
  return __uint_as_float(u << 16);
}
static __device__ __forceinline__ float bfhi(u32 u) {
  return __uint_as_float(u & 0xffff0000u);
}
static __device__ __forceinline__ u16 f2b(float f) {
  u32 u = __float_as_uint(f);
  u32 r = (u + 0x7fffu + ((u >> 16) & 1u)) >> 16;
  return (u16)r;
}

// async global->LDS, 16 B per lane; LDS dest = wave-uniform base + lane*16
static __device__ __forceinline__ void llds16(const u16* g, u16* l) {
  __builtin_amdgcn_global_load_lds(
      (const __attribute__((address_space(1))) void*)(u64)(const void*)g,
      (__attribute__((address_space(3))) void*)(u64)(void*)l, 16, 0, 0);
}

// ---------------------------------------------------------------- fallback
__global__ void mg_zero_out(float* out, int n) {
  int i = blockIdx.x * 256 + threadIdx.x;
  if (i < n) out[i] = 0.f;
}

// ---------------------------------------------------------------- x -> bf16 [NN2][64] zero-padded
__global__ void mg_cvt_x(const float* __restrict__ x, u16* __restrict__ Xb) {
  int idx = blockIdx.x * 256 + threadIdx.x;
  if (idx >= NN2 * 64) return;
  int row = idx >> 6, col = idx & 63;
  Xb[idx] = (row < NN && col < 32) ? f2b(x[row * 32 + col]) : (u16)0;
}

// ---------------------------------------------------------------- transpose
// out[n][k] = bf16(in[k][n]), zero-padded to Kpad. in is fp32.
__global__ void mg_transpose_pad(const float* __restrict__ in, u16* __restrict__ out,
                                 int K, int Nn, int Kpad) {
  int idx = blockIdx.x * 256 + threadIdx.x;
  if (idx >= Nn * Kpad) return;
  int n = idx / Kpad, k = idx - n * Kpad;
  out[idx] = (k < K) ? f2b(in[k * Nn + n]) : (u16)0;
}

// ---------------------------------------------------------------- BN -> weight fold
// Wp[j][k] = Wt[j][k]*scale[k];  bp[j] = sum_k shift[k]*Wt[j][k]
__global__ void mg_fold_w(const u16* __restrict__ Wt, const float* __restrict__ scale,
                          const float* __restrict__ shift, u16* __restrict__ Wp,
                          float* __restrict__ bp) {
  __shared__ float red[128];
  int j = blockIdx.x, t = threadIdx.x;   // 384 blocks x 128 threads
  const u16* src = Wt + (size_t)j * W3D;
  u16* dst = Wp + (size_t)j * W3D;
  float acc = 0.f;
  for (int k = t; k < W3D; k += 128) {
    float w = bf2f(src[k]);
    dst[k] = f2b(w * scale[k]);
    acc += w * shift[k];
  }
  red[t] = acc; __syncthreads();
  for (int off = 64; off; off >>= 1) {
    if (t < off) red[t] += red[t + off];
    __syncthreads();
  }
  if (t == 0) bp[j] = red[0];
}

// ---------------------------------------------------------------- CSR build
__global__ void mg_edge_histo(const int* __restrict__ ei, int* __restrict__ deg) {
  int e = blockIdx.x * 256 + threadIdx.x;
  if (e >= ETOT) return;
  int d = (e < NE) ? ei[NE + e] : (e - NE);
  atomicAdd(&deg[d], 1);
}

__global__ void mg_scan1(const int* __restrict__ in, int* __restrict__ bsum, int n) {
  __shared__ int sd[256];
  int tid = threadIdx.x;
  int base = blockIdx.x * 1024 + tid * 4;
  int s = 0;
#pragma unroll
  for (int j = 0; j < 4; ++j) { int i = base + j; if (i < n) s += in[i]; }
  sd[tid] = s; __syncthreads();
  for (int off = 128; off > 0; off >>= 1) {
    if (tid < off) sd[tid] += sd[tid + off];
    __syncthreads();
  }
  if (tid == 0) bsum[blockIdx.x] = sd[0];
}

__global__ void mg_scan2(int* __restrict__ bsum, int nb) {
  __shared__ int sd[256];
  int tid = threadIdx.x;
  int v = (tid < nb) ? bsum[tid] : 0;
  sd[tid] = v; __syncthreads();
  for (int off = 1; off < 256; off <<= 1) {
    int t = (tid >= off) ? sd[tid - off] : 0;
    __syncthreads();
    sd[tid] += t;
    __syncthreads();
  }
  if (tid < nb) bsum[tid] = sd[tid] - v;   // exclusive
}

__global__ void mg_scan3(const int* __restrict__ in, const int* __restrict__ bexcl,
                         int* __restrict__ out, int n) {
  __shared__ int sd[256];
  int tid = threadIdx.x;
  int base = blockIdx.x * 1024 + tid * 4;
  int loc[4]; int s = 0;
#pragma unroll
  for (int j = 0; j < 4; ++j) { int i = base + j; loc[j] = (i < n) ? in[i] : 0; s += loc[j]; }
  sd[tid] = s; __syncthreads();
  for (int off = 1; off < 256; off <<= 1) {
    int t = (tid >= off) ? sd[tid - off] : 0;
    __syncthreads();
    sd[tid] += t;
    __syncthreads();
  }
  int run = sd[tid] - s + bexcl[blockIdx.x];
#pragma unroll
  for (int j = 0; j < 4; ++j) {
    int i = base + j;
    if (i < n) { out[i] = run; run += loc[j]; if (i == n - 1) out[n] = run; }
  }
}

__global__ void mg_edge_scatter(const int* __restrict__ ei, int* __restrict__ fill,
                                int* __restrict__ colsrc) {
  int e = blockIdx.x * 256 + threadIdx.x;
  if (e >= ETOT) return;
  int s, d;
  if (e < NE) { s = ei[e]; d = ei[NE + e]; } else { s = e - NE; d = s; }
  int pos = atomicAdd(&fill[d], 1);
  colsrc[pos] = s;
}

__global__ void mg_graph_ptr(const int* __restrict__ batch, int* __restrict__ gptr) {
  int g = blockIdx.x * 256 + threadIdx.x;
  if (g > NG) return;
  if (g == NG) { gptr[NG] = NN; return; }
  int lo = 0, hi = NN;
  while (lo < hi) { int mid = (lo + hi) >> 1; if (batch[mid] < g) lo = mid + 1; else hi = mid; }
  gptr[g] = lo;
}

// ---------------------------------------------------------------- GEMM (bf16 MFMA)
// (round-9 configuration — best measured, ~108 us per layer GEMM)
// C = A @ B; A bf16 [NN2][K] row-padded, Bt bf16 [Nn][K]. K % 32 == 0.
// GBK=32, single barrier per K-iter via llds16 double buffer (34.8 KB LDS).
#define GBM 128
#define GBN 128
#define GBK 32
#define CP  130   // C-tile LDS row stride (u16)

__global__ __launch_bounds__(256) void mg_gemm(
    const u16* __restrict__ Ag, const u16* __restrict__ Bt,
    int Mstore, int Nn, int K,
    u16* __restrict__ Cb, const float* __restrict__ bias, int relu,
    const float* __restrict__ asrc, const float* __restrict__ adst,
    float* __restrict__ aes, float* __restrict__ aed) {
  __shared__ u16 lds[17408];   // 34.8 KB: staging A0 A1 B0 B1 (8 KB each) / C-tile
  int tid = threadIdx.x;
  int n0 = blockIdx.x * GBN, m0 = blockIdx.y * GBM;
  int lane = tid & 63, wv = tid >> 6;
  int mw = (wv & 1) * 64, nw = (wv >> 1) * 64;
  int lr = lane & 15, lq = lane >> 4;
  int rr = lane & 15, cc4 = lane >> 4;       // staging: row-in-supergroup, k-chunk

  f32x4 acc[4][4];
#pragma unroll
  for (int mi = 0; mi < 4; ++mi)
#pragma unroll
    for (int ni = 0; ni < 4; ++ni) acc[mi][ni] = (f32x4){0.f, 0.f, 0.f, 0.f};

  const u16* aB = Ag + (size_t)m0 * K + cc4 * 8;
  const u16* bB = Bt + (size_t)n0 * K + cc4 * 8;
  int niter = K >> 5;

  // stage iteration 0 into buffer 0
#pragma unroll
  for (int j = 0; j < 2; ++j) {
    int sg = wv * 2 + j, grow = sg * 16 + rr;
    llds16(aB + (size_t)grow * K, lds + sg * 512);
    llds16(bB + (size_t)grow * K, lds + 8192 + sg * 512);
  }

  for (int it = 0; it < niter; ++it) {
    __syncthreads();                         // drains stage(it); guards buf reuse
    if (it + 1 < niter) {
      int k0 = (it + 1) * GBK, b = (it + 1) & 1;
#pragma unroll
      for (int j = 0; j < 2; ++j) {
        int sg = wv * 2 + j, grow = sg * 16 + rr;
        llds16(aB + (size_t)grow * K + k0, lds + b * 4096 + sg * 512);
        llds16(bB + (size_t)grow * K + k0, lds + 8192 + b * 4096 + sg * 512);
      }
    }
    const u16* Al = lds + (it & 1) * 4096;
    const u16* Bl = lds + 8192 + (it & 1) * 4096;
    short8 af[4], bfr[4];
#pragma unroll
    for (int mi = 0; mi < 4; ++mi)
      af[mi] = *(const short8*)(Al + ((mw >> 4) + mi) * 512 + lq * 128 + lr * 8);
#pragma unroll
    for (int ni = 0; ni < 4; ++ni)
      bfr[ni] = *(const short8*)(Bl + ((nw >> 4) + ni) * 512 + lq * 128 + lr * 8);
#pragma unroll
    for (int mi = 0; mi < 4; ++mi)
#pragma unroll
      for (int ni = 0; ni < 4; ++ni)
        acc[mi][ni] = __builtin_amdgcn_mfma_f32_16x16x32_bf16(af[mi], bfr[ni], acc[mi][ni], 0, 0, 0);
  }
  __syncthreads();   // all waves done with staging buffers before C-tile reuse

  // ---- epilogue: acc -> LDS C-tile (bias/relu applied), then wide stores
  float bvv[4];
#pragma unroll
  for (int ni = 0; ni < 4; ++ni)
    bvv[ni] = bias ? bias[n0 + nw + ni * 16 + lr] : 0.f;

#pragma unroll
  for (int mi = 0; mi < 4; ++mi)
#pragma unroll
    for (int ni = 0; ni < 4; ++ni) {
      int cl = nw + ni * 16 + lr;
      int rb = mw + mi * 16 + lq * 4;
#pragma unroll
      for (int r = 0; r < 4; ++r) {
        float v = acc[mi][ni][r] + bvv[ni];
        if (relu) v = fmaxf(v, 0.f);
        lds[(rb + r) * CP + cl] = f2b(v);
      }
    }
  __syncthreads();

  int rowl = tid >> 1, half = (tid & 1) * 64;
  const u16* src = lds + rowl * CP + half;
  uint4 creg[8];
#pragma unroll
  for (int j = 0; j < 8; ++j) creg[j] = *(const uint4*)(src + j * 8);
  u16* gout = Cb + (size_t)(m0 + rowl) * Nn + n0 + half;
#pragma unroll
  for (int j = 0; j < 8; ++j) *(uint4*)(gout + j * 8) = creg[j];

  if (aes) {
    const float* ap = asrc + n0 + half;
    const float* dp = adst + n0 + half;
    float se = 0.f, de = 0.f;
#pragma unroll
    for (int j = 0; j < 8; ++j) {
      float4 a0 = *(const float4*)(ap + j * 8);
      float4 a1 = *(const float4*)(ap + j * 8 + 4);
      float4 d0 = *(const float4*)(dp + j * 8);
      float4 d1 = *(const float4*)(dp + j * 8 + 4);
      uint4 rv = creg[j];
      float v0 = bflo(rv.x), v1 = bfhi(rv.x), v2 = bflo(rv.y), v3 = bfhi(rv.y);
      float v4 = bflo(rv.z), v5 = bfhi(rv.z), v6 = bflo(rv.w), v7 = bfhi(rv.w);
      se += v0 * a0.x + v1 * a0.y + v2 * a0.z + v3 * a0.w
          + v4 * a1.x + v5 * a1.y + v6 * a1.z + v7 * a1.w;
      de += v0 * d0.x + v1 * d0.y + v2 * d0.z + v3 * d0.w
          + v4 * d1.x + v5 * d1.y + v6 * d1.z + v7 * d1.w;
    }
    se += __shfl_xor(se, 1);
    de += __shfl_xor(de, 1);
    int row = m0 + rowl;
    if ((tid & 1) == 0 && row < Mstore) {
      aes[row * 4 + blockIdx.x] = se;   // one writer per (row, head): plain store
      aed[row * 4 + blockIdx.x] = de;
    }
  }
}

// ---------------------------------------------------------------- GAT aggregate
// (round-8 version — best measured) 8 nodes/block, 2 per wave sequential.
// No max pass: softmax offset = self-loop edge score m = leaky(es[n]+ed[n]).
// Gather base scalarized via readfirstlane; depth-2 software pipeline.
// BN stats in registers -> LDS -> NSLICE slices.
__global__ __launch_bounds__(256) void mg_aggregate(
    const u16* __restrict__ B, const float* __restrict__ es,
    const float* __restrict__ ed, const int* __restrict__ rowptr,
    const int* __restrict__ colsrc, const float* __restrict__ bias,
    u16* __restrict__ A, float* __restrict__ stats) {
  __shared__ float bS[4 * W3D];
  __shared__ float bQ[4 * W3D];
  int wv = threadIdx.x >> 6, lane = threadIdx.x & 63;
  if (lane < 48) {
    int h = lane >> 4;
    int cc = lane * 8;
    float4 bv0 = *(const float4*)(bias + cc);
    float4 bv1 = *(const float4*)(bias + cc + 4);
    float stS[8], stQ[8];
#pragma unroll
    for (int j = 0; j < 8; ++j) { stS[j] = 0.f; stQ[j] = 0.f; }
#pragma unroll
    for (int sub = 0; sub < 2; ++sub) {
      int n = blockIdx.x * 8 + wv * 2 + sub;       // 12500*8 == NN exactly
      int r0 = rowptr[n], r1 = rowptr[n + 1];
      float4 edv = *(const float4*)(ed + 4 * n);
      float4 esn = *(const float4*)(es + 4 * n);
      float s0 = esn.x + edv.x; s0 = (s0 > 0.f) ? s0 : 0.2f * s0;
      float s1 = esn.y + edv.y; s1 = (s1 > 0.f) ? s1 : 0.2f * s1;
      float s2 = esn.z + edv.z; s2 = (s2 > 0.f) ? s2 : 0.2f * s2;
      float mh  = (h == 0) ? s0 : ((h == 1) ? s1 : s2);
      float edh = (h == 0) ? edv.x : ((h == 1) ? edv.y : edv.z);
      float accv[8];
#pragma unroll
      for (int j = 0; j < 8; ++j) accv[j] = 0.f;
      float ssum = 0.f;
      // depth-2 pipeline, scalar gather base
      int sA = __builtin_amdgcn_readfirstlane(colsrc[r0]);
      float4 evA = *(const float4*)(es + 4 * sA);
      uint4  rvA = *(const uint4*)(B + (size_t)sA * W3D + cc);
      float4 evB = evA; uint4 rvB = rvA;
      if (r0 + 1 < r1) {
        int sB = __builtin_amdgcn_readfirstlane(colsrc[r0 + 1]);
        evB = *(const float4*)(es + 4 * sB);
        rvB = *(const uint4*)(B + (size_t)sB * W3D + cc);
      }
      for (int r = r0; r < r1; ++r) {
        float4 ev = evA; uint4 rv = rvA;
        evA = evB; rvA = rvB;
        if (r + 2 < r1) {
          int sC = __builtin_amdgcn_readfirstlane(colsrc[r + 2]);
          evB = *(const float4*)(es + 4 * sC);
          rvB = *(const uint4*)(B + (size_t)sC * W3D + cc);
        }
        float e = ((h == 0) ? ev.x : ((h == 1) ? ev.y : ev.z)) + edh;
        e = (e > 0.f) ? e : 0.2f * e;
        float p = __expf(e - mh);
        ssum += p;
        accv[0] += p * bflo(rv.x); accv[1] += p * bfhi(rv.x);
        accv[2] += p * bflo(rv.y); accv[3] += p * bfhi(rv.y);
        accv[4] += p * bflo(rv.z); accv[5] += p * bfhi(rv.z);
        accv[6] += p * bflo(rv.w); accv[7] += p * bfhi(rv.w);
      }
      float inv = 1.0f / ssum;
      float v[8];
      v[0] = accv[0] * inv + bv0.x; v[1] = accv[1] * inv + bv0.y;
      v[2] = accv[2] * inv + bv0.z; v[3] = accv[3] * inv + bv0.w;
      v[4] = accv[4] * inv + bv1.x; v[5] = accv[5] * inv + bv1.y;
      v[6] = accv[6] * inv + bv1.z; v[7] = accv[7] * inv + bv1.w;
      uint4 st;
      st.x = (u32)f2b(v[0]) | ((u32)f2b(v[1]) << 16);
      st.y = (u32)f2b(v[2]) | ((u32)f2b(v[3]) << 16);
      st.z = (u32)f2b(v[4]) | ((u32)f2b(v[5]) << 16);
      st.w = (u32)f2b(v[6]) | ((u32)f2b(v[7]) << 16);
      *(uint4*)(A + (size_t)n * W3D + cc) = st;
#pragma unroll
      for (int j = 0; j < 8; ++j) { stS[j] += v[j]; stQ[j] += v[j] * v[j]; }
    }
    *(float4*)(bS + wv * W3D + cc)     = (float4){stS[0], stS[1], stS[2], stS[3]};
    *(float4*)(bS + wv * W3D + cc + 4) = (float4){stS[4], stS[5], stS[6], stS[7]};
    *(float4*)(bQ + wv * W3D + cc)     = (float4){stQ[0], stQ[1], stQ[2], stQ[3]};
    *(float4*)(bQ + wv * W3D + cc + 4) = (float4){stQ[4], stQ[5], stQ[6], stQ[7]};
  }
  __syncthreads();
  for (int t = threadIdx.x; t < W3D; t += 256) {
    float s = 0.f, q = 0.f;
#pragma unroll
    for (int w = 0; w < 4; ++w) { s += bS[w * W3D + t]; q += bQ[w * W3D + t]; }
    float* sl = stats + (size_t)(blockIdx.x & (NSLICE - 1)) * 768;
    atomicAdd(&sl[t], s);
    atomicAdd(&sl[W3D + t], q);
  }
}

// ---------------------------------------------------------------- BN finalize
__global__ void mg_bn_finalize(const float* __restrict__ stats, const float* __restrict__ gamma,
                               const float* __restrict__ beta, float* __restrict__ scale,
                               float* __restrict__ shift) {
  int c = threadIdx.x;   // 384 threads
  float s = 0.f, q = 0.f;
  for (int b = 0; b < NSLICE; ++b) { s += stats[b * 768 + c]; q += stats[b * 768 + W3D + c]; }
  const float invN = 1.0f / (float)NN;
  float mu = s * invN;
  float var = fmaxf(q * invN - mu * mu, 0.f);
  float inv = rsqrtf(var + 1e-5f);
  float g = gamma[c], be = beta[c];
  scale[c] = g * inv;
  shift[c] = be - mu * g * inv;
}

// ---------------------------------------------------------------- pool + head
__global__ void mg_pool(const u16* __restrict__ A, const float* __restrict__ scale,
                        const float* __restrict__ shift, const int* __restrict__ gptr,
                        float* __restrict__ pooled) {
  int g = blockIdx.x, c = threadIdx.x;   // 384 threads
  int r0 = gptr[g], r1 = gptr[g + 1];
  float acc = 0.f;
  for (int n = r0; n < r1; ++n) acc += bf2f(A[(size_t)n * W3D + c]);
  int cnt = r1 - r0;
  float v = (cnt > 0) ? (acc / (float)cnt) * scale[c] + shift[c] : 0.f;
  pooled[g * W3D + c] = v;
}

__global__ void mg_head(const float* __restrict__ pooled, const float* __restrict__ w3,
                        const float* __restrict__ b3, const float* __restrict__ w4,
                        const float* __restrict__ b4, float* __restrict__ out) {
  __shared__ float p[W3D];
  __shared__ float g2[HIDD];
  __shared__ float lg[NCLS];
  int g = blockIdx.x, t = threadIdx.x;   // 128 threads
  for (int i = t; i < W3D; i += 128) p[i] = pooled[g * W3D + i];
  __syncthreads();
  float acc = 0.f;
  for (int k = 0; k < W3D; ++k) acc += p[k] * w3[k * HIDD + t];
  g2[t] = fmaxf(acc + b3[t], 0.f);
  __syncthreads();
  if (t < NCLS) {
    float a = 0.f;
    for (int k = 0; k < HIDD; ++k) a += g2[k] * w4[k * NCLS + t];
    lg[t] = a + b4[t];
  }
  __syncthreads();
  if (t < NCLS) {
    float m = -1e30f;
#pragma unroll
    for (int j = 0; j < NCLS; ++j) m = fmaxf(m, lg[j]);
    float se = 0.f;
#pragma unroll
    for (int j = 0; j < NCLS; ++j) se += __expf(lg[j] - m);
    out[g * NCLS + t] = lg[t] - m - __logf(se);
  }
}

// ---------------------------------------------------------------- launch
extern "C" void kernel_launch(void* const* d_in, const int* in_sizes, int n_in,
                              void* d_out, int out_size, void* d_ws, size_t ws_size,
                              hipStream_t stream) {
  const float* x     = (const float*)d_in[0];
  const int*   ei    = (const int*)d_in[1];
  const int*   batch = (const int*)d_in[2];
  const float* w1    = (const float*)d_in[3];
  const float* b1    = (const float*)d_in[4];
  const float* w2    = (const float*)d_in[5];
  const float* b2    = (const float*)d_in[6];
  const float* w0    = (const float*)d_in[7];
  const float* as0   = (const float*)d_in[8];
  const float* ad0   = (const float*)d_in[9];
  const float* b0    = (const float*)d_in[10];
  const float* wl    = (const float*)d_in[11];
  const float* asl   = (const float*)d_in[12];
  const float* adl   = (const float*)d_in[13];
  const float* bl    = (const float*)d_in[14];
  const float* gamma = (const float*)d_in[15];
  const float* beta  = (const float*)d_in[16];
  const float* w3    = (const float*)d_in[17];
  const float* b3    = (const float*)d_in[18];
  const float* w4    = (const float*)d_in[19];
  const float* b4    = (const float*)d_in[20];
  float* out = (float*)d_out;

  char* w = (char*)d_ws;
  auto alloc = [&](size_t bytes) -> void* {
    void* p = (void*)w;
    w += (bytes + 255) & ~(size_t)255;
    return p;
  };
  u16*   P      = (u16*)alloc((size_t)NN2 * W3D * 2);  // gemm out / gather src
  u16*   Q      = (u16*)alloc((size_t)NN2 * W3D * 2);  // agg out / next gemm in
  float* es     = (float*)alloc((size_t)NN * 4 * 4);
  float* ed     = (float*)alloc((size_t)NN * 4 * 4);
  int*   deg    = (int*)alloc((size_t)NN * 4);
  int*   rowptr = (int*)alloc((size_t)(NN + 1) * 4);
  int*   fill   = (int*)alloc((size_t)NN * 4);
  int*   colsrc = (int*)alloc((size_t)ETOT * 4);
  int*   bsum   = (int*)alloc(256 * 4);
  float* stats  = (float*)alloc((size_t)NSLICE * 768 * 4);
  float* scale  = (float*)alloc(W3D * 4);
  float* shift  = (float*)alloc(W3D * 4);
  float* bprime = (float*)alloc(W3D * 4);
  int*   gptr   = (int*)alloc((size_t)(NG + 1) * 4);
  float* pooled = (float*)alloc((size_t)NG * W3D * 4);
  u16*   W1T    = (u16*)alloc(256 * 64 * 2);
  u16*   W2T    = (u16*)alloc(128 * 256 * 2);
  u16*   W0T    = (u16*)alloc(384 * 128 * 2);
  u16*   WlT    = (u16*)alloc((size_t)3 * 384 * 384 * 2);
  u16*   WpT    = (u16*)alloc((size_t)384 * 384 * 2);
  u16*   Xb     = Q;   // [NN2][64] bf16; Q is dead until stem2 writes it

  // Workspace too small -> clean zero output (diagnostic), no OOB
  if ((size_t)(w - (char*)d_ws) > ws_size) {
    mg_zero_out<<<(out_size + 255) / 256, 256, 0, stream>>>(out, out_size);
    return;
  }

  // input conversions
  mg_cvt_x<<<(NN2 * 64 + 255) / 256, 256, 0, stream>>>(x, Xb);
  mg_transpose_pad<<<(256 * 64 + 255) / 256, 256, 0, stream>>>(w1, W1T, 32, 256, 64);
  mg_transpose_pad<<<(128 * 256 + 255) / 256, 256, 0, stream>>>(w2, W2T, 256, 128, 256);
  mg_transpose_pad<<<(384 * 128 + 255) / 256, 256, 0, stream>>>(w0, W0T, 128, 384, 128);
  for (int i = 0; i < 3; ++i)
    mg_transpose_pad<<<(384 * 384 + 255) / 256, 256, 0, stream>>>(
        wl + (size_t)i * 384 * 384, WlT + (size_t)i * 384 * 384, 384, 384, 384);

  // CSR by dst (built once, reused by all 4 layers)
  hipMemsetAsync(deg, 0, (size_t)NN * 4, stream);
  mg_edge_histo<<<(ETOT + 255) / 256, 256, 0, stream>>>(ei, deg);
  int nb = (NN + 1023) / 1024;   // 98
  mg_scan1<<<nb, 256, 0, stream>>>(deg, bsum, NN);
  mg_scan2<<<1, 256, 0, stream>>>(bsum, nb);
  mg_scan3<<<nb, 256, 0, stream>>>(deg, bsum, rowptr, NN);
  hipMemcpyAsync(fill, rowptr, (size_t)NN * 4, hipMemcpyDeviceToDevice, stream);
  mg_edge_scatter<<<(ETOT + 255) / 256, 256, 0, stream>>>(ei, fill, colsrc);
  mg_graph_ptr<<<(NG + 1 + 255) / 256, 256, 0, stream>>>(batch, gptr);

  dim3 blk(256);
  int mtiles = NN2 / GBM;   // 782

  // stem: relu(x@W1+b1) -> relu(@W2+b2); P: [NN2][256], then Q: [NN2][128]
  mg_gemm<<<dim3(2, mtiles), blk, 0, stream>>>(Xb, W1T, NN, 256, 64,
                                               P, b1, 1,
                                               nullptr, nullptr, nullptr, nullptr);
  mg_gemm<<<dim3(1, mtiles), blk, 0, stream>>>(P, W2T, NN, 128, 256,
                                               Q, b2, 1,
                                               nullptr, nullptr, nullptr, nullptr);

  for (int i = 0; i < 4; ++i) {
    int K = (i == 0) ? 128 : 384;
    const u16* Bt;
    const float* bi_g = nullptr;   // GEMM bias (folded BN shift term)
    if (i == 0) {
      Bt = W0T;
    } else {
      // fold BN of previous layer into this layer's weights + bias
      mg_fold_w<<<384, 128, 0, stream>>>(WlT + (size_t)(i - 1) * 384 * 384,
                                         scale, shift, WpT, bprime);
      Bt = WpT;
      bi_g = bprime;
    }
    const float* as = (i == 0) ? as0 : (asl + (size_t)(i - 1) * 384);
    const float* ad = (i == 0) ? ad0 : (adl + (size_t)(i - 1) * 384);
    const float* bi = (i == 0) ? b0  : (bl  + (size_t)(i - 1) * 384);
    hipMemsetAsync(stats, 0, (size_t)NSLICE * 768 * 4, stream);
    mg_gemm<<<dim3(3, mtiles), blk, 0, stream>>>(Q, Bt, NN, W3D, K,
                                                 P, bi_g, 0,
                                                 as, ad, es, ed);
    mg_aggregate<<<NN / 8, 256, 0, stream>>>(P, es, ed, rowptr, colsrc, bi, Q, stats);
    mg_bn_finalize<<<1, 384, 0, stream>>>(stats, gamma + (size_t)i * W3D,
                                          beta + (size_t)i * W3D, scale, shift);
  }

  // global mean pool (BN3 folded in) + MLP head + log_softmax
  mg_pool<<<NG, 384, 0, stream>>>(Q, scale, shift, gptr, pooled);
  mg_head<<<NG, 128, 0, stream>>>(pooled, w3, b3, w4, b4, out);
}